// Round 14
// baseline (299.888 us; speedup 1.0000x reference)
//
#include <hip/hip_runtime.h>
#include <hip/hip_bf16.h>
#include <math.h>

typedef __attribute__((ext_vector_type(4))) float f32x4;
typedef __attribute__((ext_vector_type(2))) float f32x2;
typedef __attribute__((ext_vector_type(8))) short short8;
typedef unsigned short ushort_t;
typedef unsigned int uint_t;

__device__ __forceinline__ float b2f(unsigned short u) {
    unsigned int v = ((unsigned int)u) << 16;
    return __uint_as_float(v);
}
__device__ __forceinline__ unsigned short f2b(float f) {
    unsigned int x = __float_as_uint(f);
    unsigned int r = (x + 0x7fffu + ((x >> 16) & 1u)) >> 16;
    return (unsigned short)r;
}
__device__ __forceinline__ uint_t pack2(float a, float b) {
    return (uint_t)f2b(a) | ((uint_t)f2b(b) << 16);
}

#define XW 2432  // X row width: [h(128), agg(768), a*agg(768), b*agg(768)]

// ---------------------------------------------------------------- merged prep
// one dispatch: zero counts | pack WbT | pack Wc2T=W_post^T | conv h->X(:,0:128)
__global__ void prep_kernel(const float* __restrict__ W_pre,
                            const float* __restrict__ W_post,
                            const float* __restrict__ h,
                            int* __restrict__ counts,
                            ushort_t* __restrict__ WbT,
                            ushort_t* __restrict__ WcT,
                            ushort_t* __restrict__ X, int Nn) {
    int i = blockIdx.x * 256 + threadIdx.x;
    int n0 = Nn + 1;
    if (i < n0) { counts[i] = 0; return; }
    i -= n0;
    if (i < 256 * 128) {
        int nn = i >> 7, k = i & 127;
        float v = (nn < 128) ? W_pre[k * 128 + nn] : W_pre[(128 + k) * 128 + (nn - 128)];
        WbT[i] = f2b(v);
        return;
    }
    i -= 256 * 128;
    if (i < 128 * XW) {
        int nn = i / XW, k = i % XW;
        WcT[i] = f2b(W_post[(size_t)k * 128 + nn]);
        return;
    }
    i -= 128 * XW;
    if (i < Nn * 32) {
        int n = i >> 5, c4 = (i & 31) * 4;
        float4 hv = *(const float4*)&h[(size_t)n * 128 + c4];
        ushort4 o;
        o.x = f2b(hv.x); o.y = f2b(hv.y); o.z = f2b(hv.z); o.w = f2b(hv.w);
        *(ushort4*)&X[(size_t)n * XW + c4] = o;
    }
}

// ---------------------------------------------------------------- CSR build
__global__ void hist_kernel(const int* __restrict__ dst, int* __restrict__ counts, int E) {
    int i = blockIdx.x * 256 + threadIdx.x;
    if (i < E) atomicAdd(&counts[dst[i]], 1);
}

// single block exclusive scan; per-thread 40 elements loaded as 10 x int4
__global__ __launch_bounds__(1024) void scan_kernel(int* __restrict__ counts,
                                                    int* __restrict__ cursors, int Nn) {
    __shared__ int part[1024];
    int t = threadIdx.x;
    int base = t * 40;
    int vals[40];
#pragma unroll
    for (int c = 0; c < 10; ++c) {
        int idx = base + c * 4;
        int4 v4 = (idx + 3 < Nn) ? *(const int4*)&counts[idx]
                  : make_int4(idx < Nn ? counts[idx] : 0,
                              idx + 1 < Nn ? counts[idx + 1] : 0,
                              idx + 2 < Nn ? counts[idx + 2] : 0,
                              idx + 3 < Nn ? counts[idx + 3] : 0);
        vals[c * 4] = v4.x; vals[c * 4 + 1] = v4.y;
        vals[c * 4 + 2] = v4.z; vals[c * 4 + 3] = v4.w;
    }
    int loc[40];
    int s = 0;
#pragma unroll
    for (int i = 0; i < 40; ++i) { loc[i] = s; s += vals[i]; }
    part[t] = s;
    __syncthreads();
    for (int off = 1; off < 1024; off <<= 1) {
        int v = part[t];
        int u = (t >= off) ? part[t - off] : 0;
        __syncthreads();
        part[t] = v + u;
        __syncthreads();
    }
    int pre = (t > 0) ? part[t - 1] : 0;
#pragma unroll
    for (int i = 0; i < 40; ++i) {
        int idx = base + i;
        if (idx < Nn) { int o = pre + loc[i]; counts[idx] = o; cursors[idx] = o; }
    }
    if (t == 1023) counts[Nn] = part[1023];
}

// scatter: one aligned 16B record per CSR slot: {src, eid, eig_src_bits, 0}
__global__ void scatter_kernel(const int* __restrict__ dst, const int* __restrict__ src,
                               const float* __restrict__ eig, int* __restrict__ cursors,
                               int4* __restrict__ esl, int E) {
    int i = blockIdx.x * 256 + threadIdx.x;
    if (i < E) {
        int v = dst[i];
        int p = atomicAdd(&cursors[v], 1);
        int s = src[i];
        esl[p] = make_int4(s, i, __float_as_int(eig[s * 2 + 1]), 0);
    }
}

// ---------------------------------------------------------------- bf16 MFMA GEMM (B^T)
// pre-GEMM: C[M,256] = X[:,0:128] @ WbT^T. 128x128 tile, BK=64, 4 waves.
template <int OUT_BF16>
__global__ __launch_bounds__(256) void gemm_bt(const ushort_t* __restrict__ A, int lda,
                                               const ushort_t* __restrict__ Bt, int ldb,
                                               void* __restrict__ Cv, int ldc,
                                               int M, int K, int NT) {
    __shared__ ushort_t ldsbuf[2 * 128 * 64];
    const int tid = threadIdx.x, wid = tid >> 6, lane = tid & 63;
    int nwg = gridDim.x;
    int orig = blockIdx.x;
    int q8 = nwg >> 3, r8 = nwg & 7;
    int xcd = orig & 7, local = orig >> 3;
    int wg = (xcd < r8 ? xcd * (q8 + 1) : r8 * (q8 + 1) + (xcd - r8) * q8) + local;
    const int m0 = (wg / NT) * 128, n0 = (wg % NT) * 128;
    f32x4 acc[4][4] = {};
    const int wrow = (wid >> 1) * 64, wcol = (wid & 1) * 64;

    for (int kt = 0; kt < K; kt += 64) {
#pragma unroll
        for (int rnd = 0; rnd < 4; ++rnd) {
            int libase = rnd * 256 + wid * 64;
            {
                int lc = libase + lane;
                int r = lc >> 3, cs = lc & 7;
                int c = cs ^ (r & 7);
                int row = m0 + r; row = row < M ? row : M - 1;
                const ushort_t* g = A + (size_t)row * lda + (kt + c * 8);
                __builtin_amdgcn_global_load_lds(
                    (const __attribute__((address_space(1))) unsigned int*)g,
                    (__attribute__((address_space(3))) unsigned int*)&ldsbuf[(size_t)libase * 8],
                    16, 0, 0);
            }
            {
                int lc = libase + lane;
                int r = lc >> 3, cs = lc & 7;
                int c = cs ^ (r & 7);
                const ushort_t* g = Bt + (size_t)(n0 + r) * ldb + (kt + c * 8);
                __builtin_amdgcn_global_load_lds(
                    (const __attribute__((address_space(1))) unsigned int*)g,
                    (__attribute__((address_space(3))) unsigned int*)&ldsbuf[8192 + (size_t)libase * 8],
                    16, 0, 0);
            }
        }
        __syncthreads();
#pragma unroll
        for (int kk = 0; kk < 2; ++kk) {
            short8 af[4], bfr[4];
#pragma unroll
            for (int f = 0; f < 4; ++f) {
                int r = wrow + f * 16 + (lane & 15);
                int c16 = kk * 4 + (lane >> 4);
                int ch = r * 8 + (c16 ^ (r & 7));
                af[f] = *(const short8*)&ldsbuf[ch * 8];
            }
#pragma unroll
            for (int f = 0; f < 4; ++f) {
                int r = wcol + f * 16 + (lane & 15);
                int c16 = kk * 4 + (lane >> 4);
                int ch = r * 8 + (c16 ^ (r & 7));
                bfr[f] = *(const short8*)&ldsbuf[8192 + ch * 8];
            }
#pragma unroll
            for (int i = 0; i < 4; ++i)
#pragma unroll
                for (int j = 0; j < 4; ++j)
                    acc[i][j] = __builtin_amdgcn_mfma_f32_16x16x32_bf16(af[i], bfr[j], acc[i][j], 0, 0, 0);
        }
        __syncthreads();
    }
#pragma unroll
    for (int i = 0; i < 4; ++i)
#pragma unroll
        for (int j = 0; j < 4; ++j)
#pragma unroll
            for (int q = 0; q < 4; ++q) {
                int row = m0 + wrow + i * 16 + (lane >> 4) * 4 + q;
                int col = n0 + wcol + j * 16 + (lane & 15);
                if (row < M) {
                    if (OUT_BF16) ((ushort_t*)Cv)[(size_t)row * ldc + col] = f2b(acc[i][j][q]);
                    else          ((float*)Cv)[(size_t)row * ldc + col] = acc[i][j][q];
                }
            }
}

// ---------------------------------------------------------------- final GEMM + epilogue
// out[M,128] = relu((X[M,2432] @ WcT[128,2432]^T + b_post) * snorm) + h.
// BM=64, BN=128, BK=64, 4 waves (2x2). A read once; no O3 buffer.
__global__ __launch_bounds__(256) void gemm_final(
    const ushort_t* __restrict__ A, const ushort_t* __restrict__ Bt,
    const float* __restrict__ h, const float* __restrict__ snorm,
    const float* __restrict__ b_post, float* __restrict__ out, int M) {
    __shared__ ushort_t ldsA[64 * 64];
    __shared__ ushort_t ldsB[128 * 64];
    const int tid = threadIdx.x, wid = tid >> 6, lane = tid & 63;
    int nwg = gridDim.x, orig = blockIdx.x;
    int q8 = nwg >> 3, r8 = nwg & 7;
    int xcd = orig & 7, local = orig >> 3;
    int wg = (xcd < r8 ? xcd * (q8 + 1) : r8 * (q8 + 1) + (xcd - r8) * q8) + local;
    const int m0 = wg * 64;
    f32x4 acc[2][4] = {};
    const int wrow = (wid >> 1) * 32, wcol = (wid & 1) * 64;

    for (int kt = 0; kt < XW; kt += 64) {
        // A: 64 rows x 8 chunks = 512 chunks, 2 rounds of 256
#pragma unroll
        for (int rnd = 0; rnd < 2; ++rnd) {
            int lc = rnd * 256 + tid;
            int r = lc >> 3, cs = lc & 7;
            int c = cs ^ (r & 7);
            int row = m0 + r; row = row < M ? row : M - 1;
            const ushort_t* g = A + (size_t)row * XW + (kt + c * 8);
            __builtin_amdgcn_global_load_lds(
                (const __attribute__((address_space(1))) unsigned int*)g,
                (__attribute__((address_space(3))) unsigned int*)&ldsA[(size_t)lc * 8],
                16, 0, 0);
        }
        // B: 128 rows x 8 chunks = 1024 chunks, 4 rounds of 256
#pragma unroll
        for (int rnd = 0; rnd < 4; ++rnd) {
            int lc = rnd * 256 + tid;
            int r = lc >> 3, cs = lc & 7;
            int c = cs ^ (r & 7);
            const ushort_t* g = Bt + (size_t)r * XW + (kt + c * 8);
            __builtin_amdgcn_global_load_lds(
                (const __attribute__((address_space(1))) unsigned int*)g,
                (__attribute__((address_space(3))) unsigned int*)&ldsB[(size_t)lc * 8],
                16, 0, 0);
        }
        __syncthreads();
#pragma unroll
        for (int kk = 0; kk < 2; ++kk) {
            int c16 = kk * 4 + (lane >> 4);
            short8 af[2], bfr[4];
#pragma unroll
            for (int f = 0; f < 2; ++f) {
                int r = wrow + f * 16 + (lane & 15);
                af[f] = *(const short8*)&ldsA[(r * 8 + (c16 ^ (r & 7))) * 8];
            }
#pragma unroll
            for (int f = 0; f < 4; ++f) {
                int r = wcol + f * 16 + (lane & 15);
                bfr[f] = *(const short8*)&ldsB[(r * 8 + (c16 ^ (r & 7))) * 8];
            }
#pragma unroll
            for (int i = 0; i < 2; ++i)
#pragma unroll
                for (int j = 0; j < 4; ++j)
                    acc[i][j] = __builtin_amdgcn_mfma_f32_16x16x32_bf16(af[i], bfr[j], acc[i][j], 0, 0, 0);
        }
        __syncthreads();
    }
    // fused epilogue
#pragma unroll
    for (int i = 0; i < 2; ++i)
#pragma unroll
        for (int q = 0; q < 4; ++q) {
            int row = m0 + wrow + i * 16 + (lane >> 4) * 4 + q;
            if (row < M) {
                float sn = snorm[row];
#pragma unroll
                for (int j = 0; j < 4; ++j) {
                    int col = wcol + j * 16 + (lane & 15);
                    float v = (acc[i][j][q] + b_post[col]) * sn;
                    out[(size_t)row * 128 + col] =
                        fmaxf(v, 0.f) + h[(size_t)row * 128 + col];
                }
            }
        }
}

// ---------------------------------------------------------------- fused agg (coop)
// one wave per node; rounds of 16 edges. Literal-index broadcasts via
// v_readlane. Writes agg, a*agg, b*agg into X cols 128..2432.
#define RLI(v, l) __builtin_amdgcn_readlane((v), (l))
__global__ __launch_bounds__(256) void agg_coop(
    const ushort_t* __restrict__ PQ, ushort_t* __restrict__ X,
    const int4* __restrict__ esl, const int* __restrict__ offs,
    const float* __restrict__ eig, const float* __restrict__ h,
    const float* __restrict__ ef, const float* __restrict__ W_pre,
    const float* __restrict__ b_pre, int Nn) {
    int tid = threadIdx.x;
    int wid = tid >> 6, lane = tid & 63;
    int n = blockIdx.x * 4 + wid;
    if (n >= Nn) return;
    int off0 = offs[n], off1 = offs[n + 1];
    int deg = off1 - off0;
    int d0 = lane * 2;

    f32x2 w3r[16];
#pragma unroll
    for (int j = 0; j < 16; ++j)
        w3r[j] = *(const f32x2*)&W_pre[(256 + j) * 128 + d0];

    uint_t qw = *(const uint_t*)&PQ[(size_t)n * 256 + 128 + d0];
    float2 bp = *(const float2*)&b_pre[d0];
    f32x2 qb;
    qb.x = b2f((ushort_t)(qw & 0xffff)) + bp.x;
    qb.y = b2f((ushort_t)(qw >> 16)) + bp.y;
    float eigd = eig[n * 2 + 1];

    f32x2 s = {0.f, 0.f}, ss = {0.f, 0.f}, av = {0.f, 0.f}, dv = {0.f, 0.f};
    f32x2 mx = {-1e30f, -1e30f}, mn = {1e30f, 1e30f};
    float den = 0.f;

    for (int q0 = off0; q0 < off1; q0 += 16) {
        int cnt = off1 - q0; if (cnt > 16) cnt = 16;
        int slot = q0 + (lane & 15);
        if (slot > off1 - 1) slot = off1 - 1;
        int4 rc = esl[slot];
        int eidL = __shfl(rc.y, lane >> 2);
        float4 efv = ((const float4*)ef)[(size_t)eidL * 4 + (lane & 3)];
        uint_t pw[16];
#pragma unroll
        for (int j = 0; j < 16; ++j) {
            if (j < cnt) {
                int sj = RLI(rc.x, j);
                pw[j] = *(const uint_t*)&PQ[(size_t)sj * 256 + d0];
            }
        }
#pragma unroll
        for (int j = 0; j < 16; ++j) {
            if (j < cnt) {
                f32x2 acc = qb;
#pragma unroll
                for (int b = 0; b < 4; ++b) {
                    float va = __uint_as_float((uint_t)RLI(__float_as_int(efv.x), 4 * j + b));
                    float vb = __uint_as_float((uint_t)RLI(__float_as_int(efv.y), 4 * j + b));
                    float vc = __uint_as_float((uint_t)RLI(__float_as_int(efv.z), 4 * j + b));
                    float vd = __uint_as_float((uint_t)RLI(__float_as_int(efv.w), 4 * j + b));
                    acc = va * w3r[4 * b + 0] + acc;
                    acc = vb * w3r[4 * b + 1] + acc;
                    acc = vc * w3r[4 * b + 2] + acc;
                    acc = vd * w3r[4 * b + 3] + acc;
                }
                f32x2 m;
                m.x = b2f((ushort_t)(pw[j] & 0xffff));
                m.y = b2f((ushort_t)(pw[j] >> 16));
                m = m + acc;
                float dd = __int_as_float(RLI(rc.z, j)) - eigd;
                float ad = fabsf(dd);
                s = s + m; ss = m * m + ss;
                mx = __builtin_elementwise_max(mx, m);
                mn = __builtin_elementwise_min(mn, m);
                av = ad * m + av; dv = dd * m + dv;
                den += ad;
            }
        }
    }

    size_t xb = (size_t)n * XW + 128;
    float2 hv = *(const float2*)&h[(size_t)n * 128 + d0];
    float o[12];
    if (deg > 0) {
        float inv = 1.f / (float)deg;
        float mean0 = s.x * inv, mean1 = s.y * inv;
        float var0 = fmaxf(ss.x * inv - mean0 * mean0, 0.f);
        float var1 = fmaxf(ss.y * inv - mean1 * mean1, 0.f);
        float sd0 = sqrtf(var0 + 1e-5f), sd1 = sqrtf(var1 + 1e-5f);
        float idn = 1.f / (den + 1e-8f);
        o[0] = mean0; o[1] = mean1; o[2] = mx.x; o[3] = mx.y; o[4] = mn.x; o[5] = mn.y;
        o[6] = sd0; o[7] = sd1; o[8] = av.x * idn; o[9] = av.y * idn;
        o[10] = dv.x * idn - hv.x; o[11] = dv.y * idn - hv.y;
    } else {
#pragma unroll
        for (int k = 0; k < 12; ++k) o[k] = 0.f;
    }
    float degc = deg > 0 ? (float)deg : 1.f;
    float logd = logf(degc + 1.f);
    float amp = logd * (1.f / 2.772588722239781f);
    float att = 2.772588722239781f / logd;
#pragma unroll
    for (int a = 0; a < 6; ++a) {
        float o0 = o[2 * a], o1 = o[2 * a + 1];
        *(uint_t*)&X[xb + a * 128 + d0]        = pack2(o0, o1);
        *(uint_t*)&X[xb + 768 + a * 128 + d0]  = pack2(o0 * amp, o1 * amp);
        *(uint_t*)&X[xb + 1536 + a * 128 + d0] = pack2(o0 * att, o1 * att);
    }
}

// ---------------------------------------------------------------- launch
extern "C" void kernel_launch(void* const* d_in, const int* in_sizes, int n_in,
                              void* d_out, int out_size, void* d_ws, size_t ws_size,
                              hipStream_t stream) {
    const float* h      = (const float*)d_in[0];
    const float* ef     = (const float*)d_in[1];
    const float* eig    = (const float*)d_in[2];
    const float* snorm  = (const float*)d_in[3];
    const int*   src    = (const int*)d_in[4];
    const int*   dst    = (const int*)d_in[5];
    const float* W_pre  = (const float*)d_in[6];
    const float* b_pre  = (const float*)d_in[7];
    const float* W_post = (const float*)d_in[8];
    const float* b_post = (const float*)d_in[9];
    int Nn = in_sizes[0] / 128;
    int E  = in_sizes[4];
    float* out = (float*)d_out;

    char* ws = (char*)d_ws;
    size_t off = 0;
    auto alloc = [&](size_t bytes) {
        size_t o = off;
        off = (off + bytes + 255) & ~(size_t)255;
        return o;
    };
    size_t o_counts  = alloc(((size_t)Nn + 1) * 4);
    size_t o_cursors = alloc((size_t)Nn * 4);
    size_t o_esl     = alloc((size_t)E * 16);
    size_t o_PQ      = alloc((size_t)Nn * 256 * 2);
    size_t o_X       = alloc((size_t)Nn * XW * 2);
    size_t o_wb      = alloc(256 * 128 * 2);
    size_t o_wc      = alloc(128 * XW * 2);
    (void)ws_size;

    int*      counts  = (int*)(ws + o_counts);
    int*      cursors = (int*)(ws + o_cursors);
    int4*     esl     = (int4*)(ws + o_esl);
    ushort_t* PQ      = (ushort_t*)(ws + o_PQ);
    ushort_t* X       = (ushort_t*)(ws + o_X);
    ushort_t* WbT     = (ushort_t*)(ws + o_wb);
    ushort_t* WcT     = (ushort_t*)(ws + o_wc);

    int prep_items = (Nn + 1) + 256 * 128 + 128 * XW + Nn * 32;
    prep_kernel<<<(prep_items + 255) / 256, 256, 0, stream>>>(W_pre, W_post, h,
                                                              counts, WbT, WcT, X, Nn);
    hist_kernel<<<(E + 255) / 256, 256, 0, stream>>>(dst, counts, E);
    scan_kernel<<<1, 1024, 0, stream>>>(counts, cursors, Nn);
    scatter_kernel<<<(E + 255) / 256, 256, 0, stream>>>(dst, src, eig, cursors, esl, E);

    int mt = (Nn + 127) / 128;
    gemm_bt<1><<<mt * 2, 256, 0, stream>>>(X, XW, WbT, 128, (void*)PQ, 256, Nn, 128, 2);

    agg_coop<<<(Nn + 3) / 4, 256, 0, stream>>>(PQ, X, esl, counts, eig, h, ef,
                                               W_pre, b_pre, Nn);

    int mt64 = (Nn + 63) / 64;
    gemm_final<<<mt64, 256, 0, stream>>>(X, WcT, h, snorm, b_post, out, Nn);
}

// Round 15
// 295.164 us; speedup vs baseline: 1.0160x; 1.0160x over previous
//
#include <hip/hip_runtime.h>
#include <hip/hip_bf16.h>
#include <math.h>

typedef __attribute__((ext_vector_type(4))) float f32x4;
typedef __attribute__((ext_vector_type(2))) float f32x2;
typedef __attribute__((ext_vector_type(8))) short short8;
typedef unsigned short ushort_t;
typedef unsigned int uint_t;

__device__ __forceinline__ float b2f(unsigned short u) {
    unsigned int v = ((unsigned int)u) << 16;
    return __uint_as_float(v);
}
__device__ __forceinline__ unsigned short f2b(float f) {
    unsigned int x = __float_as_uint(f);
    unsigned int r = (x + 0x7fffu + ((x >> 16) & 1u)) >> 16;
    return (unsigned short)r;
}

// ---------------------------------------------------------------- merged prep
// one dispatch: zero counts | pack WbT | pack WcT | conv h->X(:,0:128)
__global__ void prep_kernel(const float* __restrict__ W_pre,
                            const float* __restrict__ W_post,
                            const float* __restrict__ h,
                            int* __restrict__ counts,
                            ushort_t* __restrict__ WbT,
                            ushort_t* __restrict__ WcT,
                            ushort_t* __restrict__ X, int Nn) {
    int i = blockIdx.x * 256 + threadIdx.x;
    int n0 = Nn + 1;
    if (i < n0) { counts[i] = 0; return; }
    i -= n0;
    if (i < 256 * 128) {
        int nn = i >> 7, k = i & 127;
        float v = (nn < 128) ? W_pre[k * 128 + nn] : W_pre[(128 + k) * 128 + (nn - 128)];
        WbT[i] = f2b(v);
        return;
    }
    i -= 256 * 128;
    if (i < 384 * 896) {
        int nn = i / 896, k = i % 896;
        float v;
        if (k < 128) {
            v = (nn < 128) ? W_post[k * 128 + nn] : 0.f;
        } else {
            int ka = k - 128;
            if (nn < 128)      v = W_post[(128 + ka) * 128 + nn];
            else if (nn < 256) v = W_post[(896 + ka) * 128 + (nn - 128)];
            else               v = W_post[(1664 + ka) * 128 + (nn - 256)];
        }
        WcT[i] = f2b(v);
        return;
    }
    i -= 384 * 896;
    if (i < Nn * 32) {
        int n = i >> 5, c4 = (i & 31) * 4;
        float4 hv = *(const float4*)&h[(size_t)n * 128 + c4];
        ushort4 o;
        o.x = f2b(hv.x); o.y = f2b(hv.y); o.z = f2b(hv.z); o.w = f2b(hv.w);
        *(ushort4*)&X[(size_t)n * 896 + c4] = o;
    }
}

// ---------------------------------------------------------------- CSR build
__global__ void hist_kernel(const int* __restrict__ dst, int* __restrict__ counts, int E) {
    int i = blockIdx.x * 256 + threadIdx.x;
    if (i < E) atomicAdd(&counts[dst[i]], 1);
}

// single block exclusive scan; per-thread 40 elements loaded as 10 x int4
__global__ __launch_bounds__(1024) void scan_kernel(int* __restrict__ counts,
                                                    int* __restrict__ cursors, int Nn) {
    __shared__ int part[1024];
    int t = threadIdx.x;
    int base = t * 40;
    int vals[40];
#pragma unroll
    for (int c = 0; c < 10; ++c) {
        int idx = base + c * 4;
        int4 v4 = (idx + 3 < Nn) ? *(const int4*)&counts[idx]
                  : make_int4(idx < Nn ? counts[idx] : 0,
                              idx + 1 < Nn ? counts[idx + 1] : 0,
                              idx + 2 < Nn ? counts[idx + 2] : 0,
                              idx + 3 < Nn ? counts[idx + 3] : 0);
        vals[c * 4] = v4.x; vals[c * 4 + 1] = v4.y;
        vals[c * 4 + 2] = v4.z; vals[c * 4 + 3] = v4.w;
    }
    int loc[40];
    int s = 0;
#pragma unroll
    for (int i = 0; i < 40; ++i) { loc[i] = s; s += vals[i]; }
    part[t] = s;
    __syncthreads();
    for (int off = 1; off < 1024; off <<= 1) {
        int v = part[t];
        int u = (t >= off) ? part[t - off] : 0;
        __syncthreads();
        part[t] = v + u;
        __syncthreads();
    }
    int pre = (t > 0) ? part[t - 1] : 0;
#pragma unroll
    for (int i = 0; i < 40; ++i) {
        int idx = base + i;
        if (idx < Nn) { int o = pre + loc[i]; counts[idx] = o; cursors[idx] = o; }
    }
    if (t == 1023) counts[Nn] = part[1023];
}

// scatter: one aligned 16B record per CSR slot: {src, eid, eig_src_bits, 0}
__global__ void scatter_kernel(const int* __restrict__ dst, const int* __restrict__ src,
                               const float* __restrict__ eig, int* __restrict__ cursors,
                               int4* __restrict__ esl, int E) {
    int i = blockIdx.x * 256 + threadIdx.x;
    if (i < E) {
        int v = dst[i];
        int p = atomicAdd(&cursors[v], 1);
        int s = src[i];
        esl[p] = make_int4(s, i, __float_as_int(eig[s * 2 + 1]), 0);
    }
}

// ---------------------------------------------------------------- bf16 MFMA GEMM (B^T)
// pre-GEMM: C[M,256] = X[:,0:128] @ WbT^T. 128x128 tile, BK=64, 4 waves.
template <int OUT_BF16>
__global__ __launch_bounds__(256) void gemm_bt(const ushort_t* __restrict__ A, int lda,
                                               const ushort_t* __restrict__ Bt, int ldb,
                                               void* __restrict__ Cv, int ldc,
                                               int M, int K, int NT) {
    __shared__ ushort_t ldsbuf[2 * 128 * 64];
    const int tid = threadIdx.x, wid = tid >> 6, lane = tid & 63;
    int nwg = gridDim.x;
    int orig = blockIdx.x;
    int q8 = nwg >> 3, r8 = nwg & 7;
    int xcd = orig & 7, local = orig >> 3;
    int wg = (xcd < r8 ? xcd * (q8 + 1) : r8 * (q8 + 1) + (xcd - r8) * q8) + local;
    const int m0 = (wg / NT) * 128, n0 = (wg % NT) * 128;
    f32x4 acc[4][4] = {};
    const int wrow = (wid >> 1) * 64, wcol = (wid & 1) * 64;

    for (int kt = 0; kt < K; kt += 64) {
#pragma unroll
        for (int rnd = 0; rnd < 4; ++rnd) {
            int libase = rnd * 256 + wid * 64;
            {
                int lc = libase + lane;
                int r = lc >> 3, cs = lc & 7;
                int c = cs ^ (r & 7);
                int row = m0 + r; row = row < M ? row : M - 1;
                const ushort_t* g = A + (size_t)row * lda + (kt + c * 8);
                __builtin_amdgcn_global_load_lds(
                    (const __attribute__((address_space(1))) unsigned int*)g,
                    (__attribute__((address_space(3))) unsigned int*)&ldsbuf[(size_t)libase * 8],
                    16, 0, 0);
            }
            {
                int lc = libase + lane;
                int r = lc >> 3, cs = lc & 7;
                int c = cs ^ (r & 7);
                const ushort_t* g = Bt + (size_t)(n0 + r) * ldb + (kt + c * 8);
                __builtin_amdgcn_global_load_lds(
                    (const __attribute__((address_space(1))) unsigned int*)g,
                    (__attribute__((address_space(3))) unsigned int*)&ldsbuf[8192 + (size_t)libase * 8],
                    16, 0, 0);
            }
        }
        __syncthreads();
#pragma unroll
        for (int kk = 0; kk < 2; ++kk) {
            short8 af[4], bfr[4];
#pragma unroll
            for (int f = 0; f < 4; ++f) {
                int r = wrow + f * 16 + (lane & 15);
                int c16 = kk * 4 + (lane >> 4);
                int ch = r * 8 + (c16 ^ (r & 7));
                af[f] = *(const short8*)&ldsbuf[ch * 8];
            }
#pragma unroll
            for (int f = 0; f < 4; ++f) {
                int r = wcol + f * 16 + (lane & 15);
                int c16 = kk * 4 + (lane >> 4);
                int ch = r * 8 + (c16 ^ (r & 7));
                bfr[f] = *(const short8*)&ldsbuf[8192 + ch * 8];
            }
#pragma unroll
            for (int i = 0; i < 4; ++i)
#pragma unroll
                for (int j = 0; j < 4; ++j)
                    acc[i][j] = __builtin_amdgcn_mfma_f32_16x16x32_bf16(af[i], bfr[j], acc[i][j], 0, 0, 0);
        }
        __syncthreads();
    }
#pragma unroll
    for (int i = 0; i < 4; ++i)
#pragma unroll
        for (int j = 0; j < 4; ++j)
#pragma unroll
            for (int q = 0; q < 4; ++q) {
                int row = m0 + wrow + i * 16 + (lane >> 4) * 4 + q;
                int col = n0 + wcol + j * 16 + (lane & 15);
                if (row < M) {
                    if (OUT_BF16) ((ushort_t*)Cv)[(size_t)row * ldc + col] = f2b(acc[i][j][q]);
                    else          ((float*)Cv)[(size_t)row * ldc + col] = acc[i][j][q];
                }
            }
}

// ---------------------------------------------------------------- post-GEMM + epilogue (fused)
// out[M,128] = relu((o1 + a*o2 + b*o3 + bp) * sn) + h, where [o1|o2|o3] =
// X[M,896] @ WcT[384,896]^T. BM=64, BN=384 in ONE block, 4 waves = 2(row)x2(parity).
// Wave parity p owns 16-col frags f=2k+p; the triple (c, c+128, c+256) maps to
// frags (f, f+8, f+16) — same parity — so it combines in-register.
__global__ __launch_bounds__(256) void gemm_post_fused(
    const ushort_t* __restrict__ A, const ushort_t* __restrict__ Bt,
    const float* __restrict__ h, const float* __restrict__ snorm,
    const float* __restrict__ scal, const float* __restrict__ b_post,
    float* __restrict__ out, int M) {
    __shared__ ushort_t ldsA[64 * 64];
    __shared__ ushort_t ldsB[384 * 64];
    const int tid = threadIdx.x, wid = tid >> 6, lane = tid & 63;
    int nwg = gridDim.x, orig = blockIdx.x;
    int q8 = nwg >> 3, r8 = nwg & 7;
    int xcd = orig & 7, local = orig >> 3;
    int wg = (xcd < r8 ? xcd * (q8 + 1) : r8 * (q8 + 1) + (xcd - r8) * q8) + local;
    const int m0 = wg * 64;
    f32x4 acc[2][12] = {};
    const int wrow = (wid >> 1) * 32, par = wid & 1;

    for (int kt = 0; kt < 896; kt += 64) {
        // stage A: 512 chunks, 2 rounds of 256
#pragma unroll
        for (int rnd = 0; rnd < 2; ++rnd) {
            int lc = rnd * 256 + tid;
            int r = lc >> 3, cs = lc & 7;
            int c = cs ^ (r & 7);
            int row = m0 + r; row = row < M ? row : M - 1;
            const ushort_t* g = A + (size_t)row * 896 + (kt + c * 8);
            __builtin_amdgcn_global_load_lds(
                (const __attribute__((address_space(1))) unsigned int*)g,
                (__attribute__((address_space(3))) unsigned int*)&ldsA[(size_t)lc * 8],
                16, 0, 0);
        }
        // stage B: 3072 chunks, 12 rounds of 256 (B panel is 688KB total, L2-resident)
#pragma unroll
        for (int rnd = 0; rnd < 12; ++rnd) {
            int lc = rnd * 256 + tid;
            int r = lc >> 3, cs = lc & 7;
            int c = cs ^ (r & 7);
            const ushort_t* g = Bt + (size_t)r * 896 + (kt + c * 8);
            __builtin_amdgcn_global_load_lds(
                (const __attribute__((address_space(1))) unsigned int*)g,
                (__attribute__((address_space(3))) unsigned int*)&ldsB[(size_t)lc * 8],
                16, 0, 0);
        }
        __syncthreads();
#pragma unroll
        for (int kk = 0; kk < 2; ++kk) {
            int c16 = kk * 4 + (lane >> 4);
            short8 af[2], bfr[12];
#pragma unroll
            for (int f = 0; f < 2; ++f) {
                int r = wrow + f * 16 + (lane & 15);
                af[f] = *(const short8*)&ldsA[(r * 8 + (c16 ^ (r & 7))) * 8];
            }
#pragma unroll
            for (int k = 0; k < 12; ++k) {
                int r = (2 * k + par) * 16 + (lane & 15);
                bfr[k] = *(const short8*)&ldsB[(r * 8 + (c16 ^ (r & 7))) * 8];
            }
#pragma unroll
            for (int i = 0; i < 2; ++i)
#pragma unroll
                for (int k = 0; k < 12; ++k)
                    acc[i][k] = __builtin_amdgcn_mfma_f32_16x16x32_bf16(af[i], bfr[k], acc[i][k], 0, 0, 0);
        }
        __syncthreads();
    }
    // fused epilogue: triple (k0, k0+4, k0+8) = (o1, o2, o3) of col (2k0+par)*16+(lane&15)
#pragma unroll
    for (int i = 0; i < 2; ++i)
#pragma unroll
        for (int q = 0; q < 4; ++q) {
            int row = m0 + wrow + i * 16 + (lane >> 4) * 4 + q;
            if (row < M) {
                float2 ab = *(const float2*)&scal[row * 2];
                float sn = snorm[row];
#pragma unroll
                for (int k0 = 0; k0 < 4; ++k0) {
                    int col = (2 * k0 + par) * 16 + (lane & 15);
                    float v = acc[i][k0][q] + ab.x * acc[i][k0 + 4][q]
                              + ab.y * acc[i][k0 + 8][q] + b_post[col];
                    out[(size_t)row * 128 + col] =
                        fmaxf(v * sn, 0.f) + h[(size_t)row * 128 + col];
                }
            }
        }
}

// ---------------------------------------------------------------- fused agg (coop)
// one wave per node; rounds of 16 edges. Literal-index broadcasts via
// v_readlane (SGPR, no LDS pipe); cooperative ef distribution uses one shuffle.
#define RLI(v, l) __builtin_amdgcn_readlane((v), (l))
__global__ __launch_bounds__(256) void agg_coop(
    const ushort_t* __restrict__ PQ, ushort_t* __restrict__ X,
    const int4* __restrict__ esl, const int* __restrict__ offs,
    const float* __restrict__ eig, const float* __restrict__ h,
    const float* __restrict__ ef, const float* __restrict__ W_pre,
    const float* __restrict__ b_pre, float* __restrict__ scal, int Nn) {
    int tid = threadIdx.x;
    int wid = tid >> 6, lane = tid & 63;
    int n = blockIdx.x * 4 + wid;
    if (n >= Nn) return;
    int off0 = offs[n], off1 = offs[n + 1];
    int deg = off1 - off0;
    int d0 = lane * 2;

    f32x2 w3r[16];
#pragma unroll
    for (int j = 0; j < 16; ++j)
        w3r[j] = *(const f32x2*)&W_pre[(256 + j) * 128 + d0];

    uint_t qw = *(const uint_t*)&PQ[(size_t)n * 256 + 128 + d0];
    float2 bp = *(const float2*)&b_pre[d0];
    f32x2 qb;
    qb.x = b2f((ushort_t)(qw & 0xffff)) + bp.x;
    qb.y = b2f((ushort_t)(qw >> 16)) + bp.y;
    float eigd = eig[n * 2 + 1];

    f32x2 s = {0.f, 0.f}, ss = {0.f, 0.f}, av = {0.f, 0.f}, dv = {0.f, 0.f};
    f32x2 mx = {-1e30f, -1e30f}, mn = {1e30f, 1e30f};
    float den = 0.f;

    for (int q0 = off0; q0 < off1; q0 += 16) {
        int cnt = off1 - q0; if (cnt > 16) cnt = 16;
        int slot = q0 + (lane & 15);
        if (slot > off1 - 1) slot = off1 - 1;
        int4 rc = esl[slot];
        int eidL = __shfl(rc.y, lane >> 2);
        float4 efv = ((const float4*)ef)[(size_t)eidL * 4 + (lane & 3)];
        uint_t pw[16];
#pragma unroll
        for (int j = 0; j < 16; ++j) {
            if (j < cnt) {
                int sj = RLI(rc.x, j);
                pw[j] = *(const uint_t*)&PQ[(size_t)sj * 256 + d0];
            }
        }
#pragma unroll
        for (int j = 0; j < 16; ++j) {
            if (j < cnt) {
                f32x2 acc = qb;
#pragma unroll
                for (int b = 0; b < 4; ++b) {
                    float va = __uint_as_float((uint_t)RLI(__float_as_int(efv.x), 4 * j + b));
                    float vb = __uint_as_float((uint_t)RLI(__float_as_int(efv.y), 4 * j + b));
                    float vc = __uint_as_float((uint_t)RLI(__float_as_int(efv.z), 4 * j + b));
                    float vd = __uint_as_float((uint_t)RLI(__float_as_int(efv.w), 4 * j + b));
                    acc = va * w3r[4 * b + 0] + acc;
                    acc = vb * w3r[4 * b + 1] + acc;
                    acc = vc * w3r[4 * b + 2] + acc;
                    acc = vd * w3r[4 * b + 3] + acc;
                }
                f32x2 m;
                m.x = b2f((ushort_t)(pw[j] & 0xffff));
                m.y = b2f((ushort_t)(pw[j] >> 16));
                m = m + acc;
                float dd = __int_as_float(RLI(rc.z, j)) - eigd;
                float ad = fabsf(dd);
                s = s + m; ss = m * m + ss;
                mx = __builtin_elementwise_max(mx, m);
                mn = __builtin_elementwise_min(mn, m);
                av = ad * m + av; dv = dd * m + dv;
                den += ad;
            }
        }
    }

    size_t xb = (size_t)n * 896 + 128;
    float2 hv = *(const float2*)&h[(size_t)n * 128 + d0];
    float o[12];
    if (deg > 0) {
        float inv = 1.f / (float)deg;
        float mean0 = s.x * inv, mean1 = s.y * inv;
        float var0 = fmaxf(ss.x * inv - mean0 * mean0, 0.f);
        float var1 = fmaxf(ss.y * inv - mean1 * mean1, 0.f);
        float sd0 = sqrtf(var0 + 1e-5f), sd1 = sqrtf(var1 + 1e-5f);
        float idn = 1.f / (den + 1e-8f);
        o[0] = mean0; o[1] = mean1; o[2] = mx.x; o[3] = mx.y; o[4] = mn.x; o[5] = mn.y;
        o[6] = sd0; o[7] = sd1; o[8] = av.x * idn; o[9] = av.y * idn;
        o[10] = dv.x * idn - hv.x; o[11] = dv.y * idn - hv.y;
    } else {
#pragma unroll
        for (int k = 0; k < 12; ++k) o[k] = 0.f;
    }
#pragma unroll
    for (int a = 0; a < 6; ++a) {
        uint_t w = (uint_t)f2b(o[2 * a]) | ((uint_t)f2b(o[2 * a + 1]) << 16);
        *(uint_t*)&X[xb + a * 128 + d0] = w;
    }
    if (lane == 0) {
        float degc = deg > 0 ? (float)deg : 1.f;
        float logd = logf(degc + 1.f);
        scal[n * 2] = logd * (1.f / 2.772588722239781f);
        scal[n * 2 + 1] = 2.772588722239781f / logd;
    }
}

// ---------------------------------------------------------------- launch
extern "C" void kernel_launch(void* const* d_in, const int* in_sizes, int n_in,
                              void* d_out, int out_size, void* d_ws, size_t ws_size,
                              hipStream_t stream) {
    const float* h      = (const float*)d_in[0];
    const float* ef     = (const float*)d_in[1];
    const float* eig    = (const float*)d_in[2];
    const float* snorm  = (const float*)d_in[3];
    const int*   src    = (const int*)d_in[4];
    const int*   dst    = (const int*)d_in[5];
    const float* W_pre  = (const float*)d_in[6];
    const float* b_pre  = (const float*)d_in[7];
    const float* W_post = (const float*)d_in[8];
    const float* b_post = (const float*)d_in[9];
    int Nn = in_sizes[0] / 128;
    int E  = in_sizes[4];
    float* out = (float*)d_out;

    char* ws = (char*)d_ws;
    size_t off = 0;
    auto alloc = [&](size_t bytes) {
        size_t o = off;
        off = (off + bytes + 255) & ~(size_t)255;
        return o;
    };
    size_t o_counts  = alloc(((size_t)Nn + 1) * 4);
    size_t o_cursors = alloc((size_t)Nn * 4);
    size_t o_esl     = alloc((size_t)E * 16);
    size_t o_PQ      = alloc((size_t)Nn * 256 * 2);
    size_t o_X       = alloc((size_t)Nn * 896 * 2);
    size_t o_scal    = alloc((size_t)Nn * 2 * 4);
    size_t o_wb      = alloc(256 * 128 * 2);
    size_t o_wc      = alloc(384 * 896 * 2);
    (void)ws_size;

    int*      counts  = (int*)(ws + o_counts);
    int*      cursors = (int*)(ws + o_cursors);
    int4*     esl     = (int4*)(ws + o_esl);
    ushort_t* PQ      = (ushort_t*)(ws + o_PQ);
    ushort_t* X       = (ushort_t*)(ws + o_X);
    float*    scal    = (float*)(ws + o_scal);
    ushort_t* WbT     = (ushort_t*)(ws + o_wb);
    ushort_t* WcT     = (ushort_t*)(ws + o_wc);

    int prep_items = (Nn + 1) + 256 * 128 + 384 * 896 + Nn * 32;
    prep_kernel<<<(prep_items + 255) / 256, 256, 0, stream>>>(W_pre, W_post, h,
                                                              counts, WbT, WcT, X, Nn);
    hist_kernel<<<(E + 255) / 256, 256, 0, stream>>>(dst, counts, E);
    scan_kernel<<<1, 1024, 0, stream>>>(counts, cursors, Nn);
    scatter_kernel<<<(E + 255) / 256, 256, 0, stream>>>(dst, src, eig, cursors, esl, E);

    int mt = (Nn + 127) / 128;
    gemm_bt<1><<<mt * 2, 256, 0, stream>>>(X, 896, WbT, 128, (void*)PQ, 256, Nn, 128, 2);

    agg_coop<<<(Nn + 3) / 4, 256, 0, stream>>>(PQ, X, esl, counts, eig, h, ef,
                                               W_pre, b_pre, scal, Nn);

    int mt64 = (Nn + 63) / 64;
    gemm_post_fused<<<mt64, 256, 0, stream>>>(X, WcT, h, snorm, scal, b_post, out, Nn);
}

// Round 17
// 272.475 us; speedup vs baseline: 1.1006x; 1.0833x over previous
//
#include <hip/hip_runtime.h>
#include <hip/hip_bf16.h>
#include <math.h>

typedef __attribute__((ext_vector_type(4))) float f32x4;
typedef __attribute__((ext_vector_type(2))) float f32x2;
typedef __attribute__((ext_vector_type(8))) short short8;
typedef unsigned short ushort_t;
typedef unsigned int uint_t;

__device__ __forceinline__ float b2f(unsigned short u) {
    unsigned int v = ((unsigned int)u) << 16;
    return __uint_as_float(v);
}
__device__ __forceinline__ unsigned short f2b(float f) {
    unsigned int x = __float_as_uint(f);
    unsigned int r = (x + 0x7fffu + ((x >> 16) & 1u)) >> 16;
    return (unsigned short)r;
}

// ---------------------------------------------------------------- merged prep
// one dispatch: zero counts | pack WbT | pack WcT | conv h->X(:,0:128)
__global__ void prep_kernel(const float* __restrict__ W_pre,
                            const float* __restrict__ W_post,
                            const float* __restrict__ h,
                            int* __restrict__ counts,
                            ushort_t* __restrict__ WbT,
                            ushort_t* __restrict__ WcT,
                            ushort_t* __restrict__ X, int Nn) {
    int i = blockIdx.x * 256 + threadIdx.x;
    int n0 = Nn + 1;
    if (i < n0) { counts[i] = 0; return; }
    i -= n0;
    if (i < 256 * 128) {
        int nn = i >> 7, k = i & 127;
        float v = (nn < 128) ? W_pre[k * 128 + nn] : W_pre[(128 + k) * 128 + (nn - 128)];
        WbT[i] = f2b(v);
        return;
    }
    i -= 256 * 128;
    if (i < 384 * 896) {
        int nn = i / 896, k = i % 896;
        float v;
        if (k < 128) {
            v = (nn < 128) ? W_post[k * 128 + nn] : 0.f;
        } else {
            int ka = k - 128;
            if (nn < 128)      v = W_post[(128 + ka) * 128 + nn];
            else if (nn < 256) v = W_post[(896 + ka) * 128 + (nn - 128)];
            else               v = W_post[(1664 + ka) * 128 + (nn - 256)];
        }
        WcT[i] = f2b(v);
        return;
    }
    i -= 384 * 896;
    if (i < Nn * 32) {
        int n = i >> 5, c4 = (i & 31) * 4;
        float4 hv = *(const float4*)&h[(size_t)n * 128 + c4];
        ushort4 o;
        o.x = f2b(hv.x); o.y = f2b(hv.y); o.z = f2b(hv.z); o.w = f2b(hv.w);
        *(ushort4*)&X[(size_t)n * 896 + c4] = o;
    }
}

// ---------------------------------------------------------------- CSR build
__global__ void hist_kernel(const int* __restrict__ dst, int* __restrict__ counts, int E) {
    int i = blockIdx.x * 256 + threadIdx.x;
    if (i < E) atomicAdd(&counts[dst[i]], 1);
}

// single block exclusive scan; per-thread 40 elements loaded as 10 x int4
__global__ __launch_bounds__(1024) void scan_kernel(int* __restrict__ counts,
                                                    int* __restrict__ cursors, int Nn) {
    __shared__ int part[1024];
    int t = threadIdx.x;
    int base = t * 40;
    int vals[40];
#pragma unroll
    for (int c = 0; c < 10; ++c) {
        int idx = base + c * 4;
        int4 v4 = (idx + 3 < Nn) ? *(const int4*)&counts[idx]
                  : make_int4(idx < Nn ? counts[idx] : 0,
                              idx + 1 < Nn ? counts[idx + 1] : 0,
                              idx + 2 < Nn ? counts[idx + 2] : 0,
                              idx + 3 < Nn ? counts[idx + 3] : 0);
        vals[c * 4] = v4.x; vals[c * 4 + 1] = v4.y;
        vals[c * 4 + 2] = v4.z; vals[c * 4 + 3] = v4.w;
    }
    int loc[40];
    int s = 0;
#pragma unroll
    for (int i = 0; i < 40; ++i) { loc[i] = s; s += vals[i]; }
    part[t] = s;
    __syncthreads();
    for (int off = 1; off < 1024; off <<= 1) {
        int v = part[t];
        int u = (t >= off) ? part[t - off] : 0;
        __syncthreads();
        part[t] = v + u;
        __syncthreads();
    }
    int pre = (t > 0) ? part[t - 1] : 0;
#pragma unroll
    for (int i = 0; i < 40; ++i) {
        int idx = base + i;
        if (idx < Nn) { int o = pre + loc[i]; counts[idx] = o; cursors[idx] = o; }
    }
    if (t == 1023) counts[Nn] = part[1023];
}

// scatter: one aligned 16B record per CSR slot: {src, eid, eig_src_bits, 0}
__global__ void scatter_kernel(const int* __restrict__ dst, const int* __restrict__ src,
                               const float* __restrict__ eig, int* __restrict__ cursors,
                               int4* __restrict__ esl, int E) {
    int i = blockIdx.x * 256 + threadIdx.x;
    if (i < E) {
        int v = dst[i];
        int p = atomicAdd(&cursors[v], 1);
        int s = src[i];
        esl[p] = make_int4(s, i, __float_as_int(eig[s * 2 + 1]), 0);
    }
}

// ---------------------------------------------------------------- bf16 MFMA GEMM (B^T)
// C[M,N] = A[M,K](bf16,lda) @ Bt[N,K]^T(bf16,ldb=K).  128x128 tile, BK=64, 4 waves.
template <int OUT_BF16>
__global__ __launch_bounds__(256) void gemm_bt(const ushort_t* __restrict__ A, int lda,
                                               const ushort_t* __restrict__ Bt, int ldb,
                                               void* __restrict__ Cv, int ldc,
                                               int M, int K, int NT) {
    __shared__ ushort_t ldsbuf[2 * 128 * 64];
    const int tid = threadIdx.x, wid = tid >> 6, lane = tid & 63;
    int nwg = gridDim.x;
    int orig = blockIdx.x;
    int q8 = nwg >> 3, r8 = nwg & 7;
    int xcd = orig & 7, local = orig >> 3;
    int wg = (xcd < r8 ? xcd * (q8 + 1) : r8 * (q8 + 1) + (xcd - r8) * q8) + local;
    const int m0 = (wg / NT) * 128, n0 = (wg % NT) * 128;
    f32x4 acc[4][4] = {};
    const int wrow = (wid >> 1) * 64, wcol = (wid & 1) * 64;

    for (int kt = 0; kt < K; kt += 64) {
#pragma unroll
        for (int rnd = 0; rnd < 4; ++rnd) {
            int libase = rnd * 256 + wid * 64;
            {
                int lc = libase + lane;
                int r = lc >> 3, cs = lc & 7;
                int c = cs ^ (r & 7);
                int row = m0 + r; row = row < M ? row : M - 1;
                const ushort_t* g = A + (size_t)row * lda + (kt + c * 8);
                __builtin_amdgcn_global_load_lds(
                    (const __attribute__((address_space(1))) unsigned int*)g,
                    (__attribute__((address_space(3))) unsigned int*)&ldsbuf[(size_t)libase * 8],
                    16, 0, 0);
            }
            {
                int lc = libase + lane;
                int r = lc >> 3, cs = lc & 7;
                int c = cs ^ (r & 7);
                const ushort_t* g = Bt + (size_t)(n0 + r) * ldb + (kt + c * 8);
                __builtin_amdgcn_global_load_lds(
                    (const __attribute__((address_space(1))) unsigned int*)g,
                    (__attribute__((address_space(3))) unsigned int*)&ldsbuf[8192 + (size_t)libase * 8],
                    16, 0, 0);
            }
        }
        __syncthreads();
#pragma unroll
        for (int kk = 0; kk < 2; ++kk) {
            short8 af[4], bfr[4];
#pragma unroll
            for (int f = 0; f < 4; ++f) {
                int r = wrow + f * 16 + (lane & 15);
                int c16 = kk * 4 + (lane >> 4);
                int ch = r * 8 + (c16 ^ (r & 7));
                af[f] = *(const short8*)&ldsbuf[ch * 8];
            }
#pragma unroll
            for (int f = 0; f < 4; ++f) {
                int r = wcol + f * 16 + (lane & 15);
                int c16 = kk * 4 + (lane >> 4);
                int ch = r * 8 + (c16 ^ (r & 7));
                bfr[f] = *(const short8*)&ldsbuf[8192 + ch * 8];
            }
#pragma unroll
            for (int i = 0; i < 4; ++i)
#pragma unroll
                for (int j = 0; j < 4; ++j)
                    acc[i][j] = __builtin_amdgcn_mfma_f32_16x16x32_bf16(af[i], bfr[j], acc[i][j], 0, 0, 0);
        }
        __syncthreads();
    }
#pragma unroll
    for (int i = 0; i < 4; ++i)
#pragma unroll
        for (int j = 0; j < 4; ++j)
#pragma unroll
            for (int q = 0; q < 4; ++q) {
                int row = m0 + wrow + i * 16 + (lane >> 4) * 4 + q;
                int col = n0 + wcol + j * 16 + (lane & 15);
                if (row < M) {
                    if (OUT_BF16) ((ushort_t*)Cv)[(size_t)row * ldc + col] = f2b(acc[i][j][q]);
                    else          ((float*)Cv)[(size_t)row * ldc + col] = acc[i][j][q];
                }
            }
}

// ---------------------------------------------------------------- fused agg (coop)
// one wave per node; rounds of 16 edges. Literal-index broadcasts via
// v_readlane (SGPR, no LDS pipe); cooperative ef distribution uses one shuffle.
#define RLI(v, l) __builtin_amdgcn_readlane((v), (l))
__global__ __launch_bounds__(256) void agg_coop(
    const ushort_t* __restrict__ PQ, ushort_t* __restrict__ X,
    const int4* __restrict__ esl, const int* __restrict__ offs,
    const float* __restrict__ eig, const float* __restrict__ h,
    const float* __restrict__ ef, const float* __restrict__ W_pre,
    const float* __restrict__ b_pre, float* __restrict__ scal, int Nn) {
    int tid = threadIdx.x;
    int wid = tid >> 6, lane = tid & 63;
    int n = blockIdx.x * 4 + wid;
    if (n >= Nn) return;
    int off0 = offs[n], off1 = offs[n + 1];
    int deg = off1 - off0;
    int d0 = lane * 2;

    f32x2 w3r[16];
#pragma unroll
    for (int j = 0; j < 16; ++j)
        w3r[j] = *(const f32x2*)&W_pre[(256 + j) * 128 + d0];

    uint_t qw = *(const uint_t*)&PQ[(size_t)n * 256 + 128 + d0];
    float2 bp = *(const float2*)&b_pre[d0];
    f32x2 qb;
    qb.x = b2f((ushort_t)(qw & 0xffff)) + bp.x;
    qb.y = b2f((ushort_t)(qw >> 16)) + bp.y;
    float eigd = eig[n * 2 + 1];

    f32x2 s = {0.f, 0.f}, ss = {0.f, 0.f}, av = {0.f, 0.f}, dv = {0.f, 0.f};
    f32x2 mx = {-1e30f, -1e30f}, mn = {1e30f, 1e30f};
    float den = 0.f;

    for (int q0 = off0; q0 < off1; q0 += 16) {
        int cnt = off1 - q0; if (cnt > 16) cnt = 16;
        int slot = q0 + (lane & 15);
        if (slot > off1 - 1) slot = off1 - 1;
        int4 rc = esl[slot];
        int eidL = __shfl(rc.y, lane >> 2);
        float4 efv = ((const float4*)ef)[(size_t)eidL * 4 + (lane & 3)];
        uint_t pw[16];
#pragma unroll
        for (int j = 0; j < 16; ++j) {
            if (j < cnt) {
                int sj = RLI(rc.x, j);
                pw[j] = *(const uint_t*)&PQ[(size_t)sj * 256 + d0];
            }
        }
#pragma unroll
        for (int j = 0; j < 16; ++j) {
            if (j < cnt) {
                f32x2 acc = qb;
#pragma unroll
                for (int b = 0; b < 4; ++b) {
                    float va = __uint_as_float((uint_t)RLI(__float_as_int(efv.x), 4 * j + b));
                    float vb = __uint_as_float((uint_t)RLI(__float_as_int(efv.y), 4 * j + b));
                    float vc = __uint_as_float((uint_t)RLI(__float_as_int(efv.z), 4 * j + b));
                    float vd = __uint_as_float((uint_t)RLI(__float_as_int(efv.w), 4 * j + b));
                    acc = va * w3r[4 * b + 0] + acc;
                    acc = vb * w3r[4 * b + 1] + acc;
                    acc = vc * w3r[4 * b + 2] + acc;
                    acc = vd * w3r[4 * b + 3] + acc;
                }
                f32x2 m;
                m.x = b2f((ushort_t)(pw[j] & 0xffff));
                m.y = b2f((ushort_t)(pw[j] >> 16));
                m = m + acc;
                float dd = __int_as_float(RLI(rc.z, j)) - eigd;
                float ad = fabsf(dd);
                s = s + m; ss = m * m + ss;
                mx = __builtin_elementwise_max(mx, m);
                mn = __builtin_elementwise_min(mn, m);
                av = ad * m + av; dv = dd * m + dv;
                den += ad;
            }
        }
    }

    size_t xb = (size_t)n * 896 + 128;
    float2 hv = *(const float2*)&h[(size_t)n * 128 + d0];
    float o[12];
    if (deg > 0) {
        float inv = 1.f / (float)deg;
        float mean0 = s.x * inv, mean1 = s.y * inv;
        float var0 = fmaxf(ss.x * inv - mean0 * mean0, 0.f);
        float var1 = fmaxf(ss.y * inv - mean1 * mean1, 0.f);
        float sd0 = sqrtf(var0 + 1e-5f), sd1 = sqrtf(var1 + 1e-5f);
        float idn = 1.f / (den + 1e-8f);
        o[0] = mean0; o[1] = mean1; o[2] = mx.x; o[3] = mx.y; o[4] = mn.x; o[5] = mn.y;
        o[6] = sd0; o[7] = sd1; o[8] = av.x * idn; o[9] = av.y * idn;
        o[10] = dv.x * idn - hv.x; o[11] = dv.y * idn - hv.y;
    } else {
#pragma unroll
        for (int k = 0; k < 12; ++k) o[k] = 0.f;
    }
#pragma unroll
    for (int a = 0; a < 6; ++a) {
        uint_t w = (uint_t)f2b(o[2 * a]) | ((uint_t)f2b(o[2 * a + 1]) << 16);
        *(uint_t*)&X[xb + a * 128 + d0] = w;
    }
    if (lane == 0) {
        float degc = deg > 0 ? (float)deg : 1.f;
        float logd = logf(degc + 1.f);
        scal[n * 2] = logd * (1.f / 2.772588722239781f);
        scal[n * 2 + 1] = 2.772588722239781f / logd;
    }
}

// ---------------------------------------------------------------- epilogue
__global__ __launch_bounds__(256) void epilogue_kernel(
    const float* __restrict__ O3, const float* __restrict__ h,
    const float* __restrict__ snorm, const float* __restrict__ scal,
    const float* __restrict__ b_post, float* __restrict__ out, int Nn) {
    int g = blockIdx.x * 256 + threadIdx.x;
    if (g >= Nn * 32) return;
    int n = g >> 5, c4 = (g & 31) * 4;
    float a = scal[n * 2], b = scal[n * 2 + 1], sn = snorm[n];
    const float* base = O3 + (size_t)n * 384 + c4;
    float4 o1 = *(const float4*)base;
    float4 o2 = *(const float4*)(base + 128);
    float4 o3 = *(const float4*)(base + 256);
    float4 bp = *(const float4*)&b_post[c4];
    float4 hv = *(const float4*)&h[(size_t)n * 128 + c4];
    float4 r;
    r.x = fmaxf((o1.x + a * o2.x + b * o3.x + bp.x) * sn, 0.f) + hv.x;
    r.y = fmaxf((o1.y + a * o2.y + b * o3.y + bp.y) * sn, 0.f) + hv.y;
    r.z = fmaxf((o1.z + a * o2.z + b * o3.z + bp.z) * sn, 0.f) + hv.z;
    r.w = fmaxf((o1.w + a * o2.w + b * o3.w + bp.w) * sn, 0.f) + hv.w;
    *(float4*)&out[(size_t)n * 128 + c4] = r;
}

// ---------------------------------------------------------------- launch
extern "C" void kernel_launch(void* const* d_in, const int* in_sizes, int n_in,
                              void* d_out, int out_size, void* d_ws, size_t ws_size,
                              hipStream_t stream) {
    const float* h      = (const float*)d_in[0];
    const float* ef     = (const float*)d_in[1];
    const float* eig    = (const float*)d_in[2];
    const float* snorm  = (const float*)d_in[3];
    const int*   src    = (const int*)d_in[4];
    const int*   dst    = (const int*)d_in[5];
    const float* W_pre  = (const float*)d_in[6];
    const float* b_pre  = (const float*)d_in[7];
    const float* W_post = (const float*)d_in[8];
    const float* b_post = (const float*)d_in[9];
    int Nn = in_sizes[0] / 128;
    int E  = in_sizes[4];
    float* out = (float*)d_out;

    char* ws = (char*)d_ws;
    size_t off = 0;
    auto alloc = [&](size_t bytes) {
        size_t o = off;
        off = (off + bytes + 255) & ~(size_t)255;
        return o;
    };
    size_t o_counts  = alloc(((size_t)Nn + 1) * 4);
    size_t o_cursors = alloc((size_t)Nn * 4);
    size_t o_esl     = alloc((size_t)E * 16);
    size_t o_PQ      = alloc((size_t)Nn * 256 * 2);
    size_t o_X       = alloc((size_t)Nn * 896 * 2);
    size_t o_O3      = alloc((size_t)Nn * 384 * 4);
    size_t o_scal    = alloc((size_t)Nn * 2 * 4);
    size_t o_wb      = alloc(256 * 128 * 2);
    size_t o_wc      = alloc(384 * 896 * 2);
    (void)ws_size;

    int*      counts  = (int*)(ws + o_counts);
    int*      cursors = (int*)(ws + o_cursors);
    int4*     esl     = (int4*)(ws + o_esl);
    ushort_t* PQ      = (ushort_t*)(ws + o_PQ);
    ushort_t* X       = (ushort_t*)(ws + o_X);
    float*    O3      = (float*)(ws + o_O3);
    float*    scal    = (float*)(ws + o_scal);
    ushort_t* WbT     = (ushort_t*)(ws + o_wb);
    ushort_t* WcT     = (ushort_t*)(ws + o_wc);

    int prep_items = (Nn + 1) + 256 * 128 + 384 * 896 + Nn * 32;
    prep_kernel<<<(prep_items + 255) / 256, 256, 0, stream>>>(W_pre, W_post, h,
                                                              counts, WbT, WcT, X, Nn);
    hist_kernel<<<(E + 255) / 256, 256, 0, stream>>>(dst, counts, E);
    scan_kernel<<<1, 1024, 0, stream>>>(counts, cursors, Nn);
    scatter_kernel<<<(E + 255) / 256, 256, 0, stream>>>(dst, src, eig, cursors, esl, E);

    int mt = (Nn + 127) / 128;
    gemm_bt<1><<<mt * 2, 256, 0, stream>>>(X, 896, WbT, 128, (void*)PQ, 256, Nn, 128, 2);

    agg_coop<<<(Nn + 3) / 4, 256, 0, stream>>>(PQ, X, esl, counts, eig, h, ef,
                                               W_pre, b_pre, scal, Nn);

    gemm_bt<0><<<mt * 3, 256, 0, stream>>>(X, 896, WcT, 896, (void*)O3, 384, Nn, 896, 3);

    epilogue_kernel<<<(Nn * 32 + 255) / 256, 256, 0, stream>>>(O3, h, snorm, scal, b_post,
                                                               out, Nn);
}

// Round 18
// 227.423 us; speedup vs baseline: 1.3186x; 1.1981x over previous
//
#include <hip/hip_runtime.h>
#include <hip/hip_bf16.h>
#include <math.h>

typedef __attribute__((ext_vector_type(4))) float f32x4;
typedef __attribute__((ext_vector_type(2))) float f32x2;
typedef __attribute__((ext_vector_type(8))) short short8;
typedef unsigned short ushort_t;
typedef unsigned int uint_t;

__device__ __forceinline__ float b2f(unsigned short u) {
    unsigned int v = ((unsigned int)u) << 16;
    return __uint_as_float(v);
}
__device__ __forceinline__ unsigned short f2b(float f) {
    unsigned int x = __float_as_uint(f);
    unsigned int r = (x + 0x7fffu + ((x >> 16) & 1u)) >> 16;
    return (unsigned short)r;
}

// ---------------------------------------------------------------- merged prep
// one dispatch: zero counts | pack WbT | pack WcT | conv h->X(:,0:128)
__global__ void prep_kernel(const float* __restrict__ W_pre,
                            const float* __restrict__ W_post,
                            const float* __restrict__ h,
                            int* __restrict__ counts,
                            ushort_t* __restrict__ WbT,
                            ushort_t* __restrict__ WcT,
                            ushort_t* __restrict__ X, int Nn) {
    int i = blockIdx.x * 256 + threadIdx.x;
    int n0 = Nn + 1;
    if (i < n0) { counts[i] = 0; return; }
    i -= n0;
    if (i < 256 * 128) {
        int nn = i >> 7, k = i & 127;
        float v = (nn < 128) ? W_pre[k * 128 + nn] : W_pre[(128 + k) * 128 + (nn - 128)];
        WbT[i] = f2b(v);
        return;
    }
    i -= 256 * 128;
    if (i < 384 * 896) {
        int nn = i / 896, k = i % 896;
        float v;
        if (k < 128) {
            v = (nn < 128) ? W_post[k * 128 + nn] : 0.f;
        } else {
            int ka = k - 128;
            if (nn < 128)      v = W_post[(128 + ka) * 128 + nn];
            else if (nn < 256) v = W_post[(896 + ka) * 128 + (nn - 128)];
            else               v = W_post[(1664 + ka) * 128 + (nn - 256)];
        }
        WcT[i] = f2b(v);
        return;
    }
    i -= 384 * 896;
    if (i < Nn * 32) {
        int n = i >> 5, c4 = (i & 31) * 4;
        float4 hv = *(const float4*)&h[(size_t)n * 128 + c4];
        ushort4 o;
        o.x = f2b(hv.x); o.y = f2b(hv.y); o.z = f2b(hv.z); o.w = f2b(hv.w);
        *(ushort4*)&X[(size_t)n * 896 + c4] = o;
    }
}

// ---------------------------------------------------------------- CSR build
__global__ void hist_kernel(const int* __restrict__ dst, int* __restrict__ counts, int E) {
    int i = blockIdx.x * 256 + threadIdx.x;
    if (i < E) atomicAdd(&counts[dst[i]], 1);
}

// ---- 3-phase parallel exclusive scan (Nn <= 64*1024) ----
// A: per-1024-block local exclusive scan -> localscan (cursors buf), block totals
__global__ __launch_bounds__(256) void scanA_kernel(const int* __restrict__ counts,
                                                    int* __restrict__ localscan,
                                                    int* __restrict__ blocksum, int Nn) {
    __shared__ int part[256];
    int b = blockIdx.x, t = threadIdx.x;
    int idx = b * 1024 + t * 4;
    int4 v = (idx + 3 < Nn) ? *(const int4*)&counts[idx]
             : make_int4(idx < Nn ? counts[idx] : 0,
                         idx + 1 < Nn ? counts[idx + 1] : 0,
                         idx + 2 < Nn ? counts[idx + 2] : 0,
                         idx + 3 < Nn ? counts[idx + 3] : 0);
    int s1 = v.x, s2 = v.x + v.y, s3 = s2 + v.z, tot = s3 + v.w;
    part[t] = tot;
    __syncthreads();
    for (int off = 1; off < 256; off <<= 1) {
        int x = part[t];
        int u = (t >= off) ? part[t - off] : 0;
        __syncthreads();
        part[t] = x + u;
        __syncthreads();
    }
    int pre = (t > 0) ? part[t - 1] : 0;
    if (idx < Nn) {
        if (idx + 3 < Nn) {
            *(int4*)&localscan[idx] = make_int4(pre, pre + s1, pre + s2, pre + s3);
        } else {
            localscan[idx] = pre;
            if (idx + 1 < Nn) localscan[idx + 1] = pre + s1;
            if (idx + 2 < Nn) localscan[idx + 2] = pre + s2;
        }
    }
    if (t == 255) blocksum[b] = part[255];
}

// B: single small block scans the (<=64) block totals; blocksum[nb] = grand total
__global__ __launch_bounds__(64) void scanB_kernel(int* __restrict__ blocksum, int nb) {
    __shared__ int sh[64];
    int t = threadIdx.x;
    int v = (t < nb) ? blocksum[t] : 0;
    sh[t] = v;
    __syncthreads();
    for (int off = 1; off < 64; off <<= 1) {
        int x = sh[t];
        int u = (t >= off) ? sh[t - off] : 0;
        __syncthreads();
        sh[t] = x + u;
        __syncthreads();
    }
    int pre = (t > 0) ? sh[t - 1] : 0;
    if (t < nb) blocksum[t] = pre;
    if (t == 63) blocksum[nb] = sh[63];
}

// C: add block offsets -> counts (offsets) and cursors
__global__ void scanC_kernel(int* __restrict__ localscan, const int* __restrict__ blocksum,
                             int* __restrict__ counts, int Nn, int nb) {
    int i = blockIdx.x * 256 + threadIdx.x;
    if (i < Nn) {
        int o = localscan[i] + blocksum[blockIdx.x >> 2];
        counts[i] = o;
        localscan[i] = o;   // cursors
    }
    if (i == 0) counts[Nn] = blocksum[nb];
}

// scatter: one aligned 16B record per CSR slot: {src, eid, eig_src_bits, 0}
__global__ void scatter_kernel(const int* __restrict__ dst, const int* __restrict__ src,
                               const float* __restrict__ eig, int* __restrict__ cursors,
                               int4* __restrict__ esl, int E) {
    int i = blockIdx.x * 256 + threadIdx.x;
    if (i < E) {
        int v = dst[i];
        int p = atomicAdd(&cursors[v], 1);
        int s = src[i];
        esl[p] = make_int4(s, i, __float_as_int(eig[s * 2 + 1]), 0);
    }
}

// ---------------------------------------------------------------- bf16 MFMA GEMM (B^T)
// C[M,N] = A[M,K](bf16,lda) @ Bt[N,K]^T(bf16,ldb=K).  128x128 tile, BK=64, 4 waves.
template <int OUT_BF16>
__global__ __launch_bounds__(256) void gemm_bt(const ushort_t* __restrict__ A, int lda,
                                               const ushort_t* __restrict__ Bt, int ldb,
                                               void* __restrict__ Cv, int ldc,
                                               int M, int K, int NT) {
    __shared__ ushort_t ldsbuf[2 * 128 * 64];
    const int tid = threadIdx.x, wid = tid >> 6, lane = tid & 63;
    int nwg = gridDim.x;
    int orig = blockIdx.x;
    int q8 = nwg >> 3, r8 = nwg & 7;
    int xcd = orig & 7, local = orig >> 3;
    int wg = (xcd < r8 ? xcd * (q8 + 1) : r8 * (q8 + 1) + (xcd - r8) * q8) + local;
    const int m0 = (wg / NT) * 128, n0 = (wg % NT) * 128;
    f32x4 acc[4][4] = {};
    const int wrow = (wid >> 1) * 64, wcol = (wid & 1) * 64;

    for (int kt = 0; kt < K; kt += 64) {
#pragma unroll
        for (int rnd = 0; rnd < 4; ++rnd) {
            int libase = rnd * 256 + wid * 64;
            {
                int lc = libase + lane;
                int r = lc >> 3, cs = lc & 7;
                int c = cs ^ (r & 7);
                int row = m0 + r; row = row < M ? row : M - 1;
                const ushort_t* g = A + (size_t)row * lda + (kt + c * 8);
                __builtin_amdgcn_global_load_lds(
                    (const __attribute__((address_space(1))) unsigned int*)g,
                    (__attribute__((address_space(3))) unsigned int*)&ldsbuf[(size_t)libase * 8],
                    16, 0, 0);
            }
            {
                int lc = libase + lane;
                int r = lc >> 3, cs = lc & 7;
                int c = cs ^ (r & 7);
                const ushort_t* g = Bt + (size_t)(n0 + r) * ldb + (kt + c * 8);
                __builtin_amdgcn_global_load_lds(
                    (const __attribute__((address_space(1))) unsigned int*)g,
                    (__attribute__((address_space(3))) unsigned int*)&ldsbuf[8192 + (size_t)libase * 8],
                    16, 0, 0);
            }
        }
        __syncthreads();
#pragma unroll
        for (int kk = 0; kk < 2; ++kk) {
            short8 af[4], bfr[4];
#pragma unroll
            for (int f = 0; f < 4; ++f) {
                int r = wrow + f * 16 + (lane & 15);
                int c16 = kk * 4 + (lane >> 4);
                int ch = r * 8 + (c16 ^ (r & 7));
                af[f] = *(const short8*)&ldsbuf[ch * 8];
            }
#pragma unroll
            for (int f = 0; f < 4; ++f) {
                int r = wcol + f * 16 + (lane & 15);
                int c16 = kk * 4 + (lane >> 4);
                int ch = r * 8 + (c16 ^ (r & 7));
                bfr[f] = *(const short8*)&ldsbuf[8192 + ch * 8];
            }
#pragma unroll
            for (int i = 0; i < 4; ++i)
#pragma unroll
                for (int j = 0; j < 4; ++j)
                    acc[i][j] = __builtin_amdgcn_mfma_f32_16x16x32_bf16(af[i], bfr[j], acc[i][j], 0, 0, 0);
        }
        __syncthreads();
    }
#pragma unroll
    for (int i = 0; i < 4; ++i)
#pragma unroll
        for (int j = 0; j < 4; ++j)
#pragma unroll
            for (int q = 0; q < 4; ++q) {
                int row = m0 + wrow + i * 16 + (lane >> 4) * 4 + q;
                int col = n0 + wcol + j * 16 + (lane & 15);
                if (row < M) {
                    if (OUT_BF16) ((ushort_t*)Cv)[(size_t)row * ldc + col] = f2b(acc[i][j][q]);
                    else          ((float*)Cv)[(size_t)row * ldc + col] = acc[i][j][q];
                }
            }
}

// ---------------------------------------------------------------- fused agg (coop)
// one wave per node; rounds of 16 edges. Literal-index broadcasts via
// v_readlane (SGPR, no LDS pipe); cooperative ef distribution uses one shuffle.
#define RLI(v, l) __builtin_amdgcn_readlane((v), (l))
__global__ __launch_bounds__(256) void agg_coop(
    const ushort_t* __restrict__ PQ, ushort_t* __restrict__ X,
    const int4* __restrict__ esl, const int* __restrict__ offs,
    const float* __restrict__ eig, const float* __restrict__ h,
    const float* __restrict__ ef, const float* __restrict__ W_pre,
    const float* __restrict__ b_pre, float* __restrict__ scal, int Nn) {
    int tid = threadIdx.x;
    int wid = tid >> 6, lane = tid & 63;
    int n = blockIdx.x * 4 + wid;
    if (n >= Nn) return;
    int off0 = offs[n], off1 = offs[n + 1];
    int deg = off1 - off0;
    int d0 = lane * 2;

    f32x2 w3r[16];
#pragma unroll
    for (int j = 0; j < 16; ++j)
        w3r[j] = *(const f32x2*)&W_pre[(256 + j) * 128 + d0];

    uint_t qw = *(const uint_t*)&PQ[(size_t)n * 256 + 128 + d0];
    float2 bp = *(const float2*)&b_pre[d0];
    f32x2 qb;
    qb.x = b2f((ushort_t)(qw & 0xffff)) + bp.x;
    qb.y = b2f((ushort_t)(qw >> 16)) + bp.y;
    float eigd = eig[n * 2 + 1];

    f32x2 s = {0.f, 0.f}, ss = {0.f, 0.f}, av = {0.f, 0.f}, dv = {0.f, 0.f};
    f32x2 mx = {-1e30f, -1e30f}, mn = {1e30f, 1e30f};
    float den = 0.f;

    for (int q0 = off0; q0 < off1; q0 += 16) {
        int cnt = off1 - q0; if (cnt > 16) cnt = 16;
        int slot = q0 + (lane & 15);
        if (slot > off1 - 1) slot = off1 - 1;
        int4 rc = esl[slot];
        int eidL = __shfl(rc.y, lane >> 2);
        float4 efv = ((const float4*)ef)[(size_t)eidL * 4 + (lane & 3)];
        uint_t pw[16];
#pragma unroll
        for (int j = 0; j < 16; ++j) {
            if (j < cnt) {
                int sj = RLI(rc.x, j);
                pw[j] = *(const uint_t*)&PQ[(size_t)sj * 256 + d0];
            }
        }
#pragma unroll
        for (int j = 0; j < 16; ++j) {
            if (j < cnt) {
                f32x2 acc = qb;
#pragma unroll
                for (int b = 0; b < 4; ++b) {
                    float va = __uint_as_float((uint_t)RLI(__float_as_int(efv.x), 4 * j + b));
                    float vb = __uint_as_float((uint_t)RLI(__float_as_int(efv.y), 4 * j + b));
                    float vc = __uint_as_float((uint_t)RLI(__float_as_int(efv.z), 4 * j + b));
                    float vd = __uint_as_float((uint_t)RLI(__float_as_int(efv.w), 4 * j + b));
                    acc = va * w3r[4 * b + 0] + acc;
                    acc = vb * w3r[4 * b + 1] + acc;
                    acc = vc * w3r[4 * b + 2] + acc;
                    acc = vd * w3r[4 * b + 3] + acc;
                }
                f32x2 m;
                m.x = b2f((ushort_t)(pw[j] & 0xffff));
                m.y = b2f((ushort_t)(pw[j] >> 16));
                m = m + acc;
                float dd = __int_as_float(RLI(rc.z, j)) - eigd;
                float ad = fabsf(dd);
                s = s + m; ss = m * m + ss;
                mx = __builtin_elementwise_max(mx, m);
                mn = __builtin_elementwise_min(mn, m);
                av = ad * m + av; dv = dd * m + dv;
                den += ad;
            }
        }
    }

    size_t xb = (size_t)n * 896 + 128;
    float2 hv = *(const float2*)&h[(size_t)n * 128 + d0];
    float o[12];
    if (deg > 0) {
        float inv = 1.f / (float)deg;
        float mean0 = s.x * inv, mean1 = s.y * inv;
        float var0 = fmaxf(ss.x * inv - mean0 * mean0, 0.f);
        float var1 = fmaxf(ss.y * inv - mean1 * mean1, 0.f);
        float sd0 = sqrtf(var0 + 1e-5f), sd1 = sqrtf(var1 + 1e-5f);
        float idn = 1.f / (den + 1e-8f);
        o[0] = mean0; o[1] = mean1; o[2] = mx.x; o[3] = mx.y; o[4] = mn.x; o[5] = mn.y;
        o[6] = sd0; o[7] = sd1; o[8] = av.x * idn; o[9] = av.y * idn;
        o[10] = dv.x * idn - hv.x; o[11] = dv.y * idn - hv.y;
    } else {
#pragma unroll
        for (int k = 0; k < 12; ++k) o[k] = 0.f;
    }
#pragma unroll
    for (int a = 0; a < 6; ++a) {
        uint_t w = (uint_t)f2b(o[2 * a]) | ((uint_t)f2b(o[2 * a + 1]) << 16);
        *(uint_t*)&X[xb + a * 128 + d0] = w;
    }
    if (lane == 0) {
        float degc = deg > 0 ? (float)deg : 1.f;
        float logd = logf(degc + 1.f);
        scal[n * 2] = logd * (1.f / 2.772588722239781f);
        scal[n * 2 + 1] = 2.772588722239781f / logd;
    }
}

// ---------------------------------------------------------------- epilogue (bf16 O3)
__global__ __launch_bounds__(256) void epilogue_kernel(
    const ushort_t* __restrict__ O3, const float* __restrict__ h,
    const float* __restrict__ snorm, const float* __restrict__ scal,
    const float* __restrict__ b_post, float* __restrict__ out, int Nn) {
    int g = blockIdx.x * 256 + threadIdx.x;
    if (g >= Nn * 32) return;
    int n = g >> 5, c4 = (g & 31) * 4;
    float a = scal[n * 2], b = scal[n * 2 + 1], sn = snorm[n];
    const ushort_t* base = O3 + (size_t)n * 384 + c4;
    ushort4 u1 = *(const ushort4*)base;
    ushort4 u2 = *(const ushort4*)(base + 128);
    ushort4 u3 = *(const ushort4*)(base + 256);
    float4 bp = *(const float4*)&b_post[c4];
    float4 hv = *(const float4*)&h[(size_t)n * 128 + c4];
    float4 r;
    r.x = fmaxf((b2f(u1.x) + a * b2f(u2.x) + b * b2f(u3.x) + bp.x) * sn, 0.f) + hv.x;
    r.y = fmaxf((b2f(u1.y) + a * b2f(u2.y) + b * b2f(u3.y) + bp.y) * sn, 0.f) + hv.y;
    r.z = fmaxf((b2f(u1.z) + a * b2f(u2.z) + b * b2f(u3.z) + bp.z) * sn, 0.f) + hv.z;
    r.w = fmaxf((b2f(u1.w) + a * b2f(u2.w) + b * b2f(u3.w) + bp.w) * sn, 0.f) + hv.w;
    *(float4*)&out[(size_t)n * 128 + c4] = r;
}

// ---------------------------------------------------------------- launch
extern "C" void kernel_launch(void* const* d_in, const int* in_sizes, int n_in,
                              void* d_out, int out_size, void* d_ws, size_t ws_size,
                              hipStream_t stream) {
    const float* h      = (const float*)d_in[0];
    const float* ef     = (const float*)d_in[1];
    const float* eig    = (const float*)d_in[2];
    const float* snorm  = (const float*)d_in[3];
    const int*   src    = (const int*)d_in[4];
    const int*   dst    = (const int*)d_in[5];
    const float* W_pre  = (const float*)d_in[6];
    const float* b_pre  = (const float*)d_in[7];
    const float* W_post = (const float*)d_in[8];
    const float* b_post = (const float*)d_in[9];
    int Nn = in_sizes[0] / 128;
    int E  = in_sizes[4];
    float* out = (float*)d_out;

    char* ws = (char*)d_ws;
    size_t off = 0;
    auto alloc = [&](size_t bytes) {
        size_t o = off;
        off = (off + bytes + 255) & ~(size_t)255;
        return o;
    };
    size_t o_counts  = alloc(((size_t)Nn + 1) * 4);
    size_t o_cursors = alloc((size_t)Nn * 4);
    size_t o_bsum    = alloc(65 * 4);
    size_t o_esl     = alloc((size_t)E * 16);
    size_t o_PQ      = alloc((size_t)Nn * 256 * 2);
    size_t o_X       = alloc((size_t)Nn * 896 * 2);
    size_t o_O3      = alloc((size_t)Nn * 384 * 2);
    size_t o_scal    = alloc((size_t)Nn * 2 * 4);
    size_t o_wb      = alloc(256 * 128 * 2);
    size_t o_wc      = alloc(384 * 896 * 2);
    (void)ws_size;

    int*      counts  = (int*)(ws + o_counts);
    int*      cursors = (int*)(ws + o_cursors);
    int*      bsum    = (int*)(ws + o_bsum);
    int4*     esl     = (int4*)(ws + o_esl);
    ushort_t* PQ      = (ushort_t*)(ws + o_PQ);
    ushort_t* X       = (ushort_t*)(ws + o_X);
    ushort_t* O3      = (ushort_t*)(ws + o_O3);
    float*    scal    = (float*)(ws + o_scal);
    ushort_t* WbT     = (ushort_t*)(ws + o_wb);
    ushort_t* WcT     = (ushort_t*)(ws + o_wc);

    int prep_items = (Nn + 1) + 256 * 128 + 384 * 896 + Nn * 32;
    prep_kernel<<<(prep_items + 255) / 256, 256, 0, stream>>>(W_pre, W_post, h,
                                                              counts, WbT, WcT, X, Nn);
    hist_kernel<<<(E + 255) / 256, 256, 0, stream>>>(dst, counts, E);
    int nb = (Nn + 1023) / 1024;
    scanA_kernel<<<nb, 256, 0, stream>>>(counts, cursors, bsum, Nn);
    scanB_kernel<<<1, 64, 0, stream>>>(bsum, nb);
    scanC_kernel<<<(Nn + 255) / 256, 256, 0, stream>>>(cursors, bsum, counts, Nn, nb);
    scatter_kernel<<<(E + 255) / 256, 256, 0, stream>>>(dst, src, eig, cursors, esl, E);

    int mt = (Nn + 127) / 128;
    gemm_bt<1><<<mt * 2, 256, 0, stream>>>(X, 896, WbT, 128, (void*)PQ, 256, Nn, 128, 2);

    agg_coop<<<(Nn + 3) / 4, 256, 0, stream>>>(PQ, X, esl, counts, eig, h, ef,
                                               W_pre, b_pre, scal, Nn);

    gemm_bt<1><<<mt * 3, 256, 0, stream>>>(X, 896, WcT, 896, (void*)O3, 384, Nn, 896, 3);

    epilogue_kernel<<<(Nn * 32 + 255) / 256, 256, 0, stream>>>(O3, h, snorm, scal, b_post,
                                                               out, Nn);
}